// Round 1
// baseline (554.719 us; speedup 1.0000x reference)
//
#include <hip/hip_runtime.h>
#include <hip/hip_bf16.h>
#include <math.h>

// Problem constants
#define B_  2
#define K_  512
#define SD_ 60
#define NA_ 5
#define E_  256
#define H_  4
#define D_  64
#define FF_ 1024
#define NL_ 2
#define L_  (3 * K_)          // 1536 tokens per batch
#define M_  (B_ * L_)         // 3072 rows total
#define EPS_F 1e-6f
#define LN_EPS 1e-5f
#define CHK 64                // attention chunk size
#define NC_ (L_ / CHK)        // 24 chunks per (b,h)

// ---------------------------------------------------------------------------
// Embedding + interleave: x[b, 3t+j, e]
// ---------------------------------------------------------------------------
__global__ __launch_bounds__(256) void embed_kernel(
    const float* __restrict__ rtg, const float* __restrict__ state,
    const float* __restrict__ action,
    const float* __restrict__ rtg_w, const float* __restrict__ rtg_b,
    const float* __restrict__ state_w, const float* __restrict__ state_b,
    const float* __restrict__ action_w, const float* __restrict__ action_b,
    const float* __restrict__ pos, float* __restrict__ X)
{
    int idx = blockIdx.x * 256 + threadIdx.x;     // over B*L*E
    int e = idx & (E_ - 1);
    int l = (idx >> 8) % L_;
    int b = idx / (E_ * L_);
    int j = l % 3;
    int t = l / 3;
    float val = pos[t * E_ + e];
    if (j == 0) {
        val += rtg[b * K_ + t] * rtg_w[e] + rtg_b[e];
    } else if (j == 1) {
        float a = state_b[e];
        const float* srow = state + ((size_t)b * K_ + t) * SD_;
        #pragma unroll 4
        for (int i = 0; i < SD_; i++) a += srow[i] * state_w[i * E_ + e];
        val += a;
    } else {
        float a = action_b[e];
        const float* arow = action + ((size_t)b * K_ + t) * NA_;
        #pragma unroll
        for (int i = 0; i < NA_; i++) a += arow[i] * action_w[i * E_ + e];
        val += a;
    }
    X[idx] = val;
}

// ---------------------------------------------------------------------------
// LayerNorm over E=256, one block (256 threads) per token
// ---------------------------------------------------------------------------
__global__ __launch_bounds__(256) void ln_kernel(
    const float* __restrict__ X, const float* __restrict__ g,
    const float* __restrict__ b, float* __restrict__ Y)
{
    int tok = blockIdx.x;
    int e = threadIdx.x;
    float v = X[(size_t)tok * E_ + e];
    __shared__ float red[256];
    __shared__ float s_mean, s_var;
    red[e] = v;
    __syncthreads();
    for (int s = 128; s > 0; s >>= 1) {
        if (e < s) red[e] += red[e + s];
        __syncthreads();
    }
    if (e == 0) s_mean = red[0] * (1.0f / E_);
    __syncthreads();
    float m = s_mean;
    float dv = v - m;
    red[e] = dv * dv;
    __syncthreads();
    for (int s = 128; s > 0; s >>= 1) {
        if (e < s) red[e] += red[e + s];
        __syncthreads();
    }
    if (e == 0) s_var = red[0] * (1.0f / E_);
    __syncthreads();
    float inv = rsqrtf(s_var + LN_EPS);
    Y[(size_t)tok * E_ + e] = dv * inv * g[e] + b[e];
}

// ---------------------------------------------------------------------------
// Tiled fp32 GEMM: C[M,N] = epi(A[M,K] @ Bw[K,N] + bias[N] (+ Res))
// EPI: 0 = none, 1 = exact gelu, 2 = residual add
// BM=BN=64, BK=16, 256 threads, 4x4 per thread
// ---------------------------------------------------------------------------
template <int EPI>
__global__ __launch_bounds__(256) void gemm_kernel(
    const float* __restrict__ A, const float* __restrict__ Bw,
    const float* __restrict__ bias, const float* __restrict__ Res,
    float* __restrict__ Cout, int M, int N, int Kd)
{
    __shared__ float As[16][68];
    __shared__ float Bs[16][64];
    int tid = threadIdx.x;
    int bm = blockIdx.y * 64;
    int bn = blockIdx.x * 64;

    int ar = tid >> 2;              // A row within tile (0..63)
    int ak = (tid & 3) << 2;        // A k offset {0,4,8,12}
    int bk = tid >> 4;              // B k row (0..15)
    int bn4 = (tid & 15) << 2;      // B n offset {0..60}

    float acc[4][4] = {};
    int tm = (tid >> 4) << 2;       // 0..60
    int tn = (tid & 15) << 2;       // 0..60

    for (int k0 = 0; k0 < Kd; k0 += 16) {
        float4 av = *(const float4*)(A + (size_t)(bm + ar) * Kd + k0 + ak);
        As[ak + 0][ar] = av.x;
        As[ak + 1][ar] = av.y;
        As[ak + 2][ar] = av.z;
        As[ak + 3][ar] = av.w;
        *(float4*)&Bs[bk][bn4] = *(const float4*)(Bw + (size_t)(k0 + bk) * N + bn + bn4);
        __syncthreads();
        #pragma unroll
        for (int kk = 0; kk < 16; kk++) {
            float a[4], bb[4];
            *(float4*)a  = *(const float4*)&As[kk][tm];
            *(float4*)bb = *(const float4*)&Bs[kk][tn];
            #pragma unroll
            for (int i = 0; i < 4; i++)
                #pragma unroll
                for (int j = 0; j < 4; j++)
                    acc[i][j] += a[i] * bb[j];
        }
        __syncthreads();
    }

    #pragma unroll
    for (int i = 0; i < 4; i++) {
        size_t row = (size_t)(bm + tm + i) * N + bn + tn;
        #pragma unroll
        for (int j = 0; j < 4; j++) {
            float v = acc[i][j] + bias[bn + tn + j];
            if (EPI == 1) v = 0.5f * v * (1.0f + erff(v * 0.70710678118654752f));
            if (EPI == 2) v += Res[row + j];
            Cout[row + j] = v;
        }
    }
}

// ---------------------------------------------------------------------------
// Chunked linear attention
// qkv layout: (B, L, 768) with q:[0,256) k:[256,512) v:[512,768), head-major D=64
// ---------------------------------------------------------------------------
// Pass A: per-chunk S = sum_t k_t (x) v_t  (64x64), z = sum_t k_t (64)
__global__ __launch_bounds__(256) void chunk_sum_kernel(
    const float* __restrict__ QKV, float* __restrict__ S, float* __restrict__ Z)
{
    int blk = blockIdx.x;                  // (b*H+h)*NC + c
    int c = blk % NC_;
    int bh = blk / NC_;
    int h = bh % H_;
    int b = bh / H_;
    __shared__ float Ks[64][64];
    __shared__ float Vs[64][64];
    const size_t base = ((size_t)b * L_ + (size_t)c * CHK) * 768;
    for (int idx = threadIdx.x; idx < 64 * 64; idx += 256) {
        int t = idx >> 6, d = idx & 63;
        float kv = QKV[base + (size_t)t * 768 + 256 + h * 64 + d];
        Ks[t][d] = fmaxf(kv, 0.f) + EPS_F;
        Vs[t][d] = QKV[base + (size_t)t * 768 + 512 + h * 64 + d];
    }
    __syncthreads();
    int d = threadIdx.x >> 2;
    int e0 = (threadIdx.x & 3) << 4;
    float acc[16] = {};
    float zacc = 0.f;
    for (int t = 0; t < 64; t++) {
        float kd = Ks[t][d];
        zacc += kd;
        #pragma unroll
        for (int j = 0; j < 16; j++) acc[j] += kd * Vs[t][e0 + j];
    }
    float* Sp = S + (size_t)blk * 4096 + d * 64 + e0;
    #pragma unroll
    for (int j = 0; j < 16; j++) Sp[j] = acc[j];
    if (e0 == 0) Z[(size_t)blk * 64 + d] = zacc;
}

// Pass B: exclusive prefix over chunks (in place); one block per (b,h)
__global__ __launch_bounds__(256) void chunk_prefix_kernel(
    float* __restrict__ S, float* __restrict__ Z)
{
    int bh = blockIdx.x;
    int d = threadIdx.x >> 2;
    int e0 = (threadIdx.x & 3) << 4;
    float run[16] = {};
    float runz = 0.f;
    for (int c = 0; c < NC_; c++) {
        float* Sp = S + ((size_t)(bh * NC_ + c)) * 4096 + d * 64 + e0;
        #pragma unroll
        for (int j = 0; j < 16; j++) {
            float t = Sp[j];
            Sp[j] = run[j];
            run[j] += t;
        }
        if (e0 == 0) {
            float* Zp = Z + (size_t)(bh * NC_ + c) * 64 + d;
            float t = *Zp;
            *Zp = runz;
            runz += t;
        }
    }
}

// Pass C: per chunk, per token: o = (q.KV + tril(QK^T)V) / max(q.kz + rowsum, 1e-6)
__global__ __launch_bounds__(64) void chunk_out_kernel(
    const float* __restrict__ QKV, const float* __restrict__ KV,
    const float* __restrict__ KZ, float* __restrict__ O)
{
    int blk = blockIdx.x;
    int c = blk % NC_;
    int bh = blk / NC_;
    int h = bh % H_;
    int b = bh / H_;
    __shared__ float Ks[64][64];
    __shared__ float Vs[64][64];
    __shared__ float KVs[64][64];
    __shared__ float kz[64];
    int t = threadIdx.x;  // token within chunk
    const size_t base = ((size_t)b * L_ + (size_t)c * CHK) * 768;
    const float* kvrow = KV + (size_t)blk * 4096 + t * 64;
    #pragma unroll 8
    for (int d = 0; d < 64; d++) {
        Ks[t][d]  = fmaxf(QKV[base + (size_t)t * 768 + 256 + h * 64 + d], 0.f) + EPS_F;
        Vs[t][d]  = QKV[base + (size_t)t * 768 + 512 + h * 64 + d];
        KVs[t][d] = kvrow[d];
    }
    kz[t] = KZ[(size_t)blk * 64 + t];
    float q[64];
    #pragma unroll
    for (int d = 0; d < 64; d++)
        q[d] = fmaxf(QKV[base + (size_t)t * 768 + h * 64 + d], 0.f) + EPS_F;
    __syncthreads();

    float num[64];
    #pragma unroll
    for (int e = 0; e < 64; e++) num[e] = 0.f;
    float den = 0.f;
    // global-state contribution
    #pragma unroll
    for (int d = 0; d < 64; d++) {
        float qd = q[d];
        den += qd * kz[d];
        #pragma unroll
        for (int e = 0; e < 64; e++) num[e] += qd * KVs[d][e];
    }
    // intra-chunk causal contribution
    for (int s = 0; s <= t; s++) {
        float a = 0.f;
        #pragma unroll
        for (int d = 0; d < 64; d++) a += q[d] * Ks[s][d];
        den += a;
        #pragma unroll
        for (int e = 0; e < 64; e++) num[e] += a * Vs[s][e];
    }
    float inv = 1.0f / fmaxf(den, 1e-6f);
    float* Op = O + ((size_t)b * L_ + (size_t)c * CHK + t) * E_ + h * 64;
    #pragma unroll
    for (int e = 0; e < 64; e++) Op[e] = num[e] * inv;
}

// ---------------------------------------------------------------------------
// Prediction head: out[b,t,na] = y[b, 3t+1, :] . pred_w[:,na] + pred_b[na]
// ---------------------------------------------------------------------------
__global__ __launch_bounds__(256) void pred_kernel(
    const float* __restrict__ Y, const float* __restrict__ W,
    const float* __restrict__ bias, float* __restrict__ Out)
{
    int idx = blockIdx.x * 256 + threadIdx.x;
    if (idx >= B_ * K_ * NA_) return;
    int na = idx % NA_;
    int t = (idx / NA_) % K_;
    int b = idx / (NA_ * K_);
    const float* y = Y + ((size_t)b * L_ + 3 * t + 1) * E_;
    float acc = bias[na];
    #pragma unroll 8
    for (int e = 0; e < E_; e++) acc += y[e] * W[e * NA_ + na];
    Out[idx] = acc;
}

// ---------------------------------------------------------------------------
extern "C" void kernel_launch(void* const* d_in, const int* in_sizes, int n_in,
                              void* d_out, int out_size, void* d_ws, size_t ws_size,
                              hipStream_t stream) {
    const float* rtg      = (const float*)d_in[0];
    const float* state    = (const float*)d_in[1];
    const float* action   = (const float*)d_in[2];
    const float* rtg_w    = (const float*)d_in[3];
    const float* rtg_b    = (const float*)d_in[4];
    const float* state_w  = (const float*)d_in[5];
    const float* state_b  = (const float*)d_in[6];
    const float* action_w = (const float*)d_in[7];
    const float* action_b = (const float*)d_in[8];
    const float* pos_emb  = (const float*)d_in[9];
    const float* norm1_g  = (const float*)d_in[10];
    const float* norm1_b  = (const float*)d_in[11];
    const float* qkv_w    = (const float*)d_in[12];
    const float* qkv_b    = (const float*)d_in[13];
    const float* out_w    = (const float*)d_in[14];
    const float* out_b    = (const float*)d_in[15];
    const float* norm2_g  = (const float*)d_in[16];
    const float* norm2_b  = (const float*)d_in[17];
    const float* ffn1_w   = (const float*)d_in[18];
    const float* ffn1_b   = (const float*)d_in[19];
    const float* ffn2_w   = (const float*)d_in[20];
    const float* ffn2_b   = (const float*)d_in[21];
    const float* normf_g  = (const float*)d_in[22];
    const float* normf_b  = (const float*)d_in[23];
    const float* pred_w   = (const float*)d_in[24];
    const float* pred_b   = (const float*)d_in[25];
    float* out = (float*)d_out;

    // workspace layout (floats)
    float* ws = (float*)d_ws;
    const size_t MX = (size_t)M_ * E_;        // 786432
    const size_t MQ = (size_t)M_ * 768;       // 2359296
    const size_t MH = (size_t)M_ * FF_;       // 3145728
    const size_t SS = (size_t)B_ * H_ * NC_ * 4096;  // 786432
    float* x   = ws;
    float* y   = x + MX;
    float* qkv = y + MX;
    float* att = qkv + MQ;
    float* h1  = att + MX;
    float* S   = h1 + MH;
    float* Z   = S + SS;

    // 1. embed + interleave
    embed_kernel<<<(B_ * L_ * E_) / 256, 256, 0, stream>>>(
        rtg, state, action, rtg_w, rtg_b, state_w, state_b,
        action_w, action_b, pos_emb, x);

    for (int i = 0; i < NL_; i++) {
        // LN1
        ln_kernel<<<M_, 256, 0, stream>>>(x, norm1_g + i * E_, norm1_b + i * E_, y);
        // QKV gemm: (3072,768,256)
        gemm_kernel<0><<<dim3(768 / 64, M_ / 64), 256, 0, stream>>>(
            y, qkv_w + (size_t)i * E_ * 768, qkv_b + i * 768, nullptr, qkv,
            M_, 768, E_);
        // chunked linear attention
        chunk_sum_kernel<<<B_ * H_ * NC_, 256, 0, stream>>>(qkv, S, Z);
        chunk_prefix_kernel<<<B_ * H_, 256, 0, stream>>>(S, Z);
        chunk_out_kernel<<<B_ * H_ * NC_, 64, 0, stream>>>(qkv, S, Z, att);
        // out proj + residual: x = x + att @ out_w + out_b
        gemm_kernel<2><<<dim3(E_ / 64, M_ / 64), 256, 0, stream>>>(
            att, out_w + (size_t)i * E_ * E_, out_b + i * E_, x, x,
            M_, E_, E_);
        // LN2
        ln_kernel<<<M_, 256, 0, stream>>>(x, norm2_g + i * E_, norm2_b + i * E_, y);
        // FFN1 + gelu
        gemm_kernel<1><<<dim3(FF_ / 64, M_ / 64), 256, 0, stream>>>(
            y, ffn1_w + (size_t)i * E_ * FF_, ffn1_b + i * FF_, nullptr, h1,
            M_, FF_, E_);
        // FFN2 + residual
        gemm_kernel<2><<<dim3(E_ / 64, M_ / 64), 256, 0, stream>>>(
            h1, ffn2_w + (size_t)i * FF_ * E_, ffn2_b + i * E_, x, x,
            M_, E_, FF_);
    }
    // final LN
    ln_kernel<<<M_, 256, 0, stream>>>(x, normf_g, normf_b, y);
    // prediction head
    pred_kernel<<<(B_ * K_ * NA_ + 255) / 256, 256, 0, stream>>>(
        y, pred_w, pred_b, out);
}

// Round 2
// 408.979 us; speedup vs baseline: 1.3564x; 1.3564x over previous
//
#include <hip/hip_runtime.h>
#include <hip/hip_bf16.h>
#include <math.h>

// Problem constants
#define B_  2
#define K_  512
#define SD_ 60
#define NA_ 5
#define E_  256
#define H_  4
#define D_  64
#define FF_ 1024
#define NL_ 2
#define L_  (3 * K_)          // 1536 tokens per batch
#define M_  (B_ * L_)         // 3072 rows total
#define EPS_F 1e-6f
#define LN_EPS 1e-5f
#define CHK 64                // attention chunk size
#define NC_ (L_ / CHK)        // 24 chunks per (b,h)

using bf16x8 = __attribute__((ext_vector_type(8))) short;
using f32x4  = __attribute__((ext_vector_type(4))) float;
typedef unsigned short u16;

__device__ inline u16 f2b(float v) {
    __hip_bfloat16 h = __float2bfloat16(v);
    return *(u16*)&h;
}

// ---------------------------------------------------------------------------
// Weight convert + transpose: W[K][N] fp32 -> Wt[N][K] bf16, 32x32 tiles
// ---------------------------------------------------------------------------
__global__ __launch_bounds__(256) void wconv_kernel(
    const float* __restrict__ qkv_w, const float* __restrict__ out_w,
    const float* __restrict__ ffn1_w, const float* __restrict__ ffn2_w,
    u16* __restrict__ qkvT, u16* __restrict__ outT,
    u16* __restrict__ f1T, u16* __restrict__ f2T)
{
    int tb = blockIdx.x;
    int layer = tb / 768;
    int r = tb % 768;
    const float* src; u16* dst; int K, N, tidx;
    if (r < 192)      { src = qkv_w  + layer * 196608; dst = qkvT + layer * 196608; K = 256;  N = 768;  tidx = r; }
    else if (r < 256) { src = out_w  + layer * 65536;  dst = outT + layer * 65536;  K = 256;  N = 256;  tidx = r - 192; }
    else if (r < 512) { src = ffn1_w + layer * 262144; dst = f1T  + layer * 262144; K = 256;  N = 1024; tidx = r - 256; }
    else              { src = ffn2_w + layer * 262144; dst = f2T  + layer * 262144; K = 1024; N = 256;  tidx = r - 512; }
    int tilesN = N >> 5;
    int k0 = (tidx / tilesN) << 5;
    int n0 = (tidx % tilesN) << 5;
    __shared__ u16 T[32][33];
    int c = threadIdx.x & 31, r0 = threadIdx.x >> 5;
    for (int rr = r0; rr < 32; rr += 8)
        T[rr][c] = f2b(src[(size_t)(k0 + rr) * N + n0 + c]);
    __syncthreads();
    for (int rr = r0; rr < 32; rr += 8)
        dst[(size_t)(n0 + rr) * K + k0 + c] = T[c][rr];
}

// ---------------------------------------------------------------------------
// Embedding + interleave: x[b, 3t+j, e]  (fp32 residual stream)
// ---------------------------------------------------------------------------
__global__ __launch_bounds__(256) void embed_kernel(
    const float* __restrict__ rtg, const float* __restrict__ state,
    const float* __restrict__ action,
    const float* __restrict__ rtg_w, const float* __restrict__ rtg_b,
    const float* __restrict__ state_w, const float* __restrict__ state_b,
    const float* __restrict__ action_w, const float* __restrict__ action_b,
    const float* __restrict__ pos, float* __restrict__ X)
{
    int idx = blockIdx.x * 256 + threadIdx.x;     // over B*L*E
    int e = idx & (E_ - 1);
    int l = (idx >> 8) % L_;
    int b = idx / (E_ * L_);
    int j = l % 3;
    int t = l / 3;
    float val = pos[t * E_ + e];
    if (j == 0) {
        val += rtg[b * K_ + t] * rtg_w[e] + rtg_b[e];
    } else if (j == 1) {
        float a = state_b[e];
        const float* srow = state + ((size_t)b * K_ + t) * SD_;
        #pragma unroll 4
        for (int i = 0; i < SD_; i++) a += srow[i] * state_w[i * E_ + e];
        val += a;
    } else {
        float a = action_b[e];
        const float* arow = action + ((size_t)b * K_ + t) * NA_;
        #pragma unroll
        for (int i = 0; i < NA_; i++) a += arow[i] * action_w[i * E_ + e];
        val += a;
    }
    X[idx] = val;
}

// ---------------------------------------------------------------------------
// LayerNorm, one wave per token (E=256, 4 elems/lane), no __syncthreads
// ---------------------------------------------------------------------------
__device__ inline void st4o(float* p, float a, float b, float c, float d) {
    *(float4*)p = make_float4(a, b, c, d);
}
__device__ inline void st4o(u16* p, float a, float b, float c, float d) {
    ushort4 u; u.x = f2b(a); u.y = f2b(b); u.z = f2b(c); u.w = f2b(d);
    *(ushort4*)p = u;
}

template <typename OutT>
__global__ __launch_bounds__(256) void ln_kernel(
    const float* __restrict__ X, const float* __restrict__ g,
    const float* __restrict__ b, OutT* __restrict__ Y)
{
    int tok = blockIdx.x * 4 + (threadIdx.x >> 6);
    int lane = threadIdx.x & 63;
    float4 v = *(const float4*)(X + (size_t)tok * E_ + lane * 4);
    float s = v.x + v.y + v.z + v.w;
    #pragma unroll
    for (int o = 32; o; o >>= 1) s += __shfl_xor(s, o, 64);
    float mean = s * (1.f / E_);
    float dx = v.x - mean, dy = v.y - mean, dz = v.z - mean, dw = v.w - mean;
    float q = dx * dx + dy * dy + dz * dz + dw * dw;
    #pragma unroll
    for (int o = 32; o; o >>= 1) q += __shfl_xor(q, o, 64);
    float inv = rsqrtf(q * (1.f / E_) + LN_EPS);
    float4 gv = *(const float4*)(g + lane * 4);
    float4 bv = *(const float4*)(b + lane * 4);
    st4o(Y + (size_t)tok * E_ + lane * 4,
         dx * inv * gv.x + bv.x, dy * inv * gv.y + bv.y,
         dz * inv * gv.z + bv.z, dw * inv * gv.w + bv.w);
}

// ---------------------------------------------------------------------------
// MFMA bf16 GEMM: C[M,N] = epi(A[M,K]bf16 @ Bt[N,K]bf16^T + bias (+Res))
// 128x128 tile, 256 threads = 4 waves (2x2 of 64x64), BK=32
// EPI: 0 none, 1 exact gelu, 2 residual add
// ---------------------------------------------------------------------------
template <int EPI, typename OutT>
__global__ __launch_bounds__(256) void mgemm(
    const u16* __restrict__ A, const u16* __restrict__ Bt,
    const float* __restrict__ bias, const float* __restrict__ Res,
    OutT* __restrict__ C, int M, int N, int Kd)
{
    __shared__ __align__(16) u16 As[128 * 40];
    __shared__ __align__(16) u16 Bs[128 * 40];
    int tid = threadIdx.x;
    int bm = blockIdx.y * 128, bn = blockIdx.x * 128;
    int wave = tid >> 6, lane = tid & 63;
    int wm = (wave >> 1) * 64, wn = (wave & 1) * 64;
    int lr = lane & 15, kg = lane >> 4;

    // staging: 512 16B-segments per matrix tile; 2 per thread
    int s0 = tid, s1 = tid + 256;
    int r0 = s0 >> 2, g0 = (s0 & 3) * 8;
    int r1 = s1 >> 2, g1 = (s1 & 3) * 8;

    f32x4 acc[4][4] = {};

    for (int k0 = 0; k0 < Kd; k0 += 32) {
        uint4 a0 = *(const uint4*)(A + (size_t)(bm + r0) * Kd + k0 + g0);
        uint4 a1 = *(const uint4*)(A + (size_t)(bm + r1) * Kd + k0 + g1);
        uint4 b0 = *(const uint4*)(Bt + (size_t)(bn + r0) * Kd + k0 + g0);
        uint4 b1 = *(const uint4*)(Bt + (size_t)(bn + r1) * Kd + k0 + g1);
        __syncthreads();
        *(uint4*)&As[r0 * 40 + g0] = a0;
        *(uint4*)&As[r1 * 40 + g1] = a1;
        *(uint4*)&Bs[r0 * 40 + g0] = b0;
        *(uint4*)&Bs[r1 * 40 + g1] = b1;
        __syncthreads();
        bf16x8 af[4], bg[4];
        #pragma unroll
        for (int i = 0; i < 4; i++)
            af[i] = *(const bf16x8*)&As[(wm + i * 16 + lr) * 40 + kg * 8];
        #pragma unroll
        for (int j = 0; j < 4; j++)
            bg[j] = *(const bf16x8*)&Bs[(wn + j * 16 + lr) * 40 + kg * 8];
        #pragma unroll
        for (int i = 0; i < 4; i++)
            #pragma unroll
            for (int j = 0; j < 4; j++)
                acc[i][j] = __builtin_amdgcn_mfma_f32_16x16x32_bf16(
                    af[i], bg[j], acc[i][j], 0, 0, 0);
    }

    int crow = (lane >> 4) * 4;
    int ccol = lane & 15;
    #pragma unroll
    for (int i = 0; i < 4; i++) {
        #pragma unroll
        for (int j = 0; j < 4; j++) {
            int col = bn + wn + j * 16 + ccol;
            float bc = bias[col];
            #pragma unroll
            for (int r = 0; r < 4; r++) {
                int row = bm + wm + i * 16 + crow + r;
                float v = acc[i][j][r] + bc;
                if (EPI == 1) v = 0.5f * v * (1.0f + erff(v * 0.70710678118654752f));
                if (EPI == 2) v += Res[(size_t)row * N + col];
                if constexpr (sizeof(OutT) == 2)
                    C[(size_t)row * N + col] = f2b(v);
                else
                    C[(size_t)row * N + col] = v;
            }
        }
    }
}

// ---------------------------------------------------------------------------
// Chunked linear attention (qkv fp32: (B,L,768) q|k|v head-major D=64)
// ---------------------------------------------------------------------------
__global__ __launch_bounds__(256) void chunk_sum_kernel(
    const float* __restrict__ QKV, float* __restrict__ S, float* __restrict__ Z)
{
    int blk = blockIdx.x;                  // (b*H+h)*NC + c
    int c = blk % NC_;
    int bh = blk / NC_;
    int h = bh % H_;
    int b = bh / H_;
    __shared__ float Ks[64][64];
    __shared__ float Vs[64][64];
    const size_t base = ((size_t)b * L_ + (size_t)c * CHK) * 768;
    for (int idx = threadIdx.x; idx < 64 * 64; idx += 256) {
        int t = idx >> 6, d = idx & 63;
        float kv = QKV[base + (size_t)t * 768 + 256 + h * 64 + d];
        Ks[t][d] = fmaxf(kv, 0.f) + EPS_F;
        Vs[t][d] = QKV[base + (size_t)t * 768 + 512 + h * 64 + d];
    }
    __syncthreads();
    int d = threadIdx.x >> 2;
    int e0 = (threadIdx.x & 3) << 4;
    float acc[16] = {};
    float zacc = 0.f;
    for (int t = 0; t < 64; t++) {
        float kd = Ks[t][d];
        zacc += kd;
        #pragma unroll
        for (int j = 0; j < 16; j++) acc[j] += kd * Vs[t][e0 + j];
    }
    float* Sp = S + (size_t)blk * 4096 + d * 64 + e0;
    #pragma unroll
    for (int j = 0; j < 16; j++) Sp[j] = acc[j];
    if (e0 == 0) Z[(size_t)blk * 64 + d] = zacc;
}

__global__ __launch_bounds__(256) void chunk_prefix_kernel(
    float* __restrict__ S, float* __restrict__ Z)
{
    int bh = blockIdx.x;
    int d = threadIdx.x >> 2;
    int e0 = (threadIdx.x & 3) << 4;
    float run[16] = {};
    float runz = 0.f;
    for (int c = 0; c < NC_; c++) {
        float* Sp = S + ((size_t)(bh * NC_ + c)) * 4096 + d * 64 + e0;
        #pragma unroll
        for (int j = 0; j < 16; j++) {
            float t = Sp[j];
            Sp[j] = run[j];
            run[j] += t;
        }
        if (e0 == 0) {
            float* Zp = Z + (size_t)(bh * NC_ + c) * 64 + d;
            float t = *Zp;
            *Zp = runz;
            runz += t;
        }
    }
}

__global__ __launch_bounds__(64) void chunk_out_kernel(
    const float* __restrict__ QKV, const float* __restrict__ KV,
    const float* __restrict__ KZ, u16* __restrict__ O)
{
    int blk = blockIdx.x;
    int c = blk % NC_;
    int bh = blk / NC_;
    int h = bh % H_;
    int b = bh / H_;
    __shared__ float Ks[64][64];
    __shared__ float Vs[64][64];
    __shared__ float KVs[64][64];
    __shared__ float kz[64];
    int t = threadIdx.x;  // token within chunk
    const size_t base = ((size_t)b * L_ + (size_t)c * CHK) * 768;
    const float* kvrow = KV + (size_t)blk * 4096 + t * 64;
    #pragma unroll 8
    for (int d = 0; d < 64; d++) {
        Ks[t][d]  = fmaxf(QKV[base + (size_t)t * 768 + 256 + h * 64 + d], 0.f) + EPS_F;
        Vs[t][d]  = QKV[base + (size_t)t * 768 + 512 + h * 64 + d];
        KVs[t][d] = kvrow[d];
    }
    kz[t] = KZ[(size_t)blk * 64 + t];
    float q[64];
    #pragma unroll
    for (int d = 0; d < 64; d++)
        q[d] = fmaxf(QKV[base + (size_t)t * 768 + h * 64 + d], 0.f) + EPS_F;
    __syncthreads();

    float num[64];
    #pragma unroll
    for (int e = 0; e < 64; e++) num[e] = 0.f;
    float den = 0.f;
    #pragma unroll
    for (int d = 0; d < 64; d++) {
        float qd = q[d];
        den += qd * kz[d];
        #pragma unroll
        for (int e = 0; e < 64; e++) num[e] += qd * KVs[d][e];
    }
    for (int s = 0; s <= t; s++) {
        float a = 0.f;
        #pragma unroll
        for (int d = 0; d < 64; d++) a += q[d] * Ks[s][d];
        den += a;
        #pragma unroll
        for (int e = 0; e < 64; e++) num[e] += a * Vs[s][e];
    }
    float inv = 1.0f / fmaxf(den, 1e-6f);
    u16* Op = O + ((size_t)b * L_ + (size_t)c * CHK + t) * E_ + h * 64;
    #pragma unroll
    for (int e = 0; e < 64; e++) Op[e] = f2b(num[e] * inv);
}

// ---------------------------------------------------------------------------
// Prediction head: out[b,t,na] = y[b, 3t+1, :] . pred_w[:,na] + pred_b[na]
// ---------------------------------------------------------------------------
__global__ __launch_bounds__(256) void pred_kernel(
    const float* __restrict__ Y, const float* __restrict__ W,
    const float* __restrict__ bias, float* __restrict__ Out)
{
    int idx = blockIdx.x * 256 + threadIdx.x;
    if (idx >= B_ * K_ * NA_) return;
    int na = idx % NA_;
    int t = (idx / NA_) % K_;
    int b = idx / (NA_ * K_);
    const float* y = Y + ((size_t)b * L_ + 3 * t + 1) * E_;
    float acc = bias[na];
    #pragma unroll 8
    for (int e = 0; e < E_; e++) acc += y[e] * W[e * NA_ + na];
    Out[idx] = acc;
}

// ---------------------------------------------------------------------------
extern "C" void kernel_launch(void* const* d_in, const int* in_sizes, int n_in,
                              void* d_out, int out_size, void* d_ws, size_t ws_size,
                              hipStream_t stream) {
    const float* rtg      = (const float*)d_in[0];
    const float* state    = (const float*)d_in[1];
    const float* action   = (const float*)d_in[2];
    const float* rtg_w    = (const float*)d_in[3];
    const float* rtg_b    = (const float*)d_in[4];
    const float* state_w  = (const float*)d_in[5];
    const float* state_b  = (const float*)d_in[6];
    const float* action_w = (const float*)d_in[7];
    const float* action_b = (const float*)d_in[8];
    const float* pos_emb  = (const float*)d_in[9];
    const float* norm1_g  = (const float*)d_in[10];
    const float* norm1_b  = (const float*)d_in[11];
    const float* qkv_w    = (const float*)d_in[12];
    const float* qkv_b    = (const float*)d_in[13];
    const float* out_w    = (const float*)d_in[14];
    const float* out_b    = (const float*)d_in[15];
    const float* norm2_g  = (const float*)d_in[16];
    const float* norm2_b  = (const float*)d_in[17];
    const float* ffn1_w   = (const float*)d_in[18];
    const float* ffn1_b   = (const float*)d_in[19];
    const float* ffn2_w   = (const float*)d_in[20];
    const float* ffn2_b   = (const float*)d_in[21];
    const float* normf_g  = (const float*)d_in[22];
    const float* normf_b  = (const float*)d_in[23];
    const float* pred_w   = (const float*)d_in[24];
    const float* pred_b   = (const float*)d_in[25];
    float* out = (float*)d_out;

    // workspace layout
    float* ws = (float*)d_ws;
    float* x    = ws;                        // 786432 f
    float* qkv  = x + 786432;                // 2359296 f
    float* S    = qkv + 2359296;             // 786432 f
    float* Z    = S + 786432;                // 12288 f
    float* yf   = Z + 12288;                 // 786432 f
    u16*   yb   = (u16*)(yf + 786432);       // 786432 u16
    u16*   att  = yb + 786432;               // 786432
    u16*   h1   = att + 786432;              // 3145728
    u16*   qkvT = h1 + 3145728;              // 393216
    u16*   outT = qkvT + 393216;             // 131072
    u16*   f1T  = outT + 131072;             // 524288
    u16*   f2T  = f1T + 524288;              // 524288

    wconv_kernel<<<1536, 256, 0, stream>>>(qkv_w, out_w, ffn1_w, ffn2_w,
                                           qkvT, outT, f1T, f2T);
    embed_kernel<<<(B_ * L_ * E_) / 256, 256, 0, stream>>>(
        rtg, state, action, rtg_w, rtg_b, state_w, state_b,
        action_w, action_b, pos_emb, x);

    for (int i = 0; i < NL_; i++) {
        ln_kernel<u16><<<M_ / 4, 256, 0, stream>>>(
            x, norm1_g + i * E_, norm1_b + i * E_, yb);
        mgemm<0, float><<<dim3(768 / 128, M_ / 128), 256, 0, stream>>>(
            yb, qkvT + (size_t)i * 196608, qkv_b + i * 768, nullptr, qkv,
            M_, 768, E_);
        chunk_sum_kernel<<<B_ * H_ * NC_, 256, 0, stream>>>(qkv, S, Z);
        chunk_prefix_kernel<<<B_ * H_, 256, 0, stream>>>(S, Z);
        chunk_out_kernel<<<B_ * H_ * NC_, 64, 0, stream>>>(qkv, S, Z, att);
        mgemm<2, float><<<dim3(E_ / 128, M_ / 128), 256, 0, stream>>>(
            att, outT + (size_t)i * 65536, out_b + i * E_, x, x,
            M_, E_, E_);
        ln_kernel<u16><<<M_ / 4, 256, 0, stream>>>(
            x, norm2_g + i * E_, norm2_b + i * E_, yb);
        mgemm<1, u16><<<dim3(FF_ / 128, M_ / 128), 256, 0, stream>>>(
            yb, f1T + (size_t)i * 262144, ffn1_b + i * FF_, nullptr, h1,
            M_, FF_, E_);
        mgemm<2, float><<<dim3(E_ / 128, M_ / 128), 256, 0, stream>>>(
            h1, f2T + (size_t)i * 262144, ffn2_b + i * E_, x, x,
            M_, E_, FF_);
    }
    ln_kernel<float><<<M_ / 4, 256, 0, stream>>>(x, normf_g, normf_b, yf);
    pred_kernel<<<(B_ * K_ * NA_ + 255) / 256, 256, 0, stream>>>(
        yf, pred_w, pred_b, out);
}

// Round 3
// 333.454 us; speedup vs baseline: 1.6636x; 1.2265x over previous
//
#include <hip/hip_runtime.h>
#include <hip/hip_bf16.h>
#include <math.h>

// Problem constants
#define B_  2
#define K_  512
#define SD_ 60
#define NA_ 5
#define E_  256
#define H_  4
#define D_  64
#define FF_ 1024
#define NL_ 2
#define L_  (3 * K_)          // 1536 tokens per batch
#define M_  (B_ * L_)         // 3072 rows total
#define EPS_F 1e-6f
#define LN_EPS 1e-5f
#define CHK 64                // attention chunk size
#define NC_ (L_ / CHK)        // 24 chunks per (b,h)

using bf16x8 = __attribute__((ext_vector_type(8))) short;
using f32x4  = __attribute__((ext_vector_type(4))) float;
typedef unsigned short u16;

__device__ inline u16 f2b(float v) {
    __hip_bfloat16 h = __float2bfloat16(v);
    return *(u16*)&h;
}
__device__ inline float b2f(u16 v) {
    __hip_bfloat16 h = *(__hip_bfloat16*)&v;
    return __bfloat162float(h);
}

// ---------------------------------------------------------------------------
// Weight convert + transpose: W[K][N] fp32 -> Wt[N][K] bf16, 32x32 tiles
// ---------------------------------------------------------------------------
__global__ __launch_bounds__(256) void wconv_kernel(
    const float* __restrict__ qkv_w, const float* __restrict__ out_w,
    const float* __restrict__ ffn1_w, const float* __restrict__ ffn2_w,
    u16* __restrict__ qkvT, u16* __restrict__ outT,
    u16* __restrict__ f1T, u16* __restrict__ f2T)
{
    int tb = blockIdx.x;
    int layer = tb / 768;
    int r = tb % 768;
    const float* src; u16* dst; int K, N, tidx;
    if (r < 192)      { src = qkv_w  + layer * 196608; dst = qkvT + layer * 196608; K = 256;  N = 768;  tidx = r; }
    else if (r < 256) { src = out_w  + layer * 65536;  dst = outT + layer * 65536;  K = 256;  N = 256;  tidx = r - 192; }
    else if (r < 512) { src = ffn1_w + layer * 262144; dst = f1T  + layer * 262144; K = 256;  N = 1024; tidx = r - 256; }
    else              { src = ffn2_w + layer * 262144; dst = f2T  + layer * 262144; K = 1024; N = 256;  tidx = r - 512; }
    int tilesN = N >> 5;
    int k0 = (tidx / tilesN) << 5;
    int n0 = (tidx % tilesN) << 5;
    __shared__ u16 T[32][33];
    int c = threadIdx.x & 31, r0 = threadIdx.x >> 5;
    for (int rr = r0; rr < 32; rr += 8)
        T[rr][c] = f2b(src[(size_t)(k0 + rr) * N + n0 + c]);
    __syncthreads();
    for (int rr = r0; rr < 32; rr += 8)
        dst[(size_t)(n0 + rr) * K + k0 + c] = T[c][rr];
}

// ---------------------------------------------------------------------------
// Embedding + interleave: x[b, 3t+j, e]  (fp32 residual stream)
// ---------------------------------------------------------------------------
__global__ __launch_bounds__(256) void embed_kernel(
    const float* __restrict__ rtg, const float* __restrict__ state,
    const float* __restrict__ action,
    const float* __restrict__ rtg_w, const float* __restrict__ rtg_b,
    const float* __restrict__ state_w, const float* __restrict__ state_b,
    const float* __restrict__ action_w, const float* __restrict__ action_b,
    const float* __restrict__ pos, float* __restrict__ X)
{
    int idx = blockIdx.x * 256 + threadIdx.x;     // over B*L*E
    int e = idx & (E_ - 1);
    int l = (idx >> 8) % L_;
    int b = idx / (E_ * L_);
    int j = l % 3;
    int t = l / 3;
    float val = pos[t * E_ + e];
    if (j == 0) {
        val += rtg[b * K_ + t] * rtg_w[e] + rtg_b[e];
    } else if (j == 1) {
        float a = state_b[e];
        const float* srow = state + ((size_t)b * K_ + t) * SD_;
        #pragma unroll 4
        for (int i = 0; i < SD_; i++) a += srow[i] * state_w[i * E_ + e];
        val += a;
    } else {
        float a = action_b[e];
        const float* arow = action + ((size_t)b * K_ + t) * NA_;
        #pragma unroll
        for (int i = 0; i < NA_; i++) a += arow[i] * action_w[i * E_ + e];
        val += a;
    }
    X[idx] = val;
}

// ---------------------------------------------------------------------------
// LayerNorm, one wave per token (E=256, 4 elems/lane)
// ---------------------------------------------------------------------------
__device__ inline void st4o(float* p, float a, float b, float c, float d) {
    *(float4*)p = make_float4(a, b, c, d);
}
__device__ inline void st4o(u16* p, float a, float b, float c, float d) {
    ushort4 u; u.x = f2b(a); u.y = f2b(b); u.z = f2b(c); u.w = f2b(d);
    *(ushort4*)p = u;
}

template <typename OutT>
__global__ __launch_bounds__(256) void ln_kernel(
    const float* __restrict__ X, const float* __restrict__ g,
    const float* __restrict__ b, OutT* __restrict__ Y)
{
    int tok = blockIdx.x * 4 + (threadIdx.x >> 6);
    int lane = threadIdx.x & 63;
    float4 v = *(const float4*)(X + (size_t)tok * E_ + lane * 4);
    float s = v.x + v.y + v.z + v.w;
    #pragma unroll
    for (int o = 32; o; o >>= 1) s += __shfl_xor(s, o, 64);
    float mean = s * (1.f / E_);
    float dx = v.x - mean, dy = v.y - mean, dz = v.z - mean, dw = v.w - mean;
    float q = dx * dx + dy * dy + dz * dz + dw * dw;
    #pragma unroll
    for (int o = 32; o; o >>= 1) q += __shfl_xor(q, o, 64);
    float inv = rsqrtf(q * (1.f / E_) + LN_EPS);
    float4 gv = *(const float4*)(g + lane * 4);
    float4 bv = *(const float4*)(b + lane * 4);
    st4o(Y + (size_t)tok * E_ + lane * 4,
         dx * inv * gv.x + bv.x, dy * inv * gv.y + bv.y,
         dz * inv * gv.z + bv.z, dw * inv * gv.w + bv.w);
}

// ---------------------------------------------------------------------------
// MFMA bf16 GEMM: C[M,N] = epi(A[M,K]bf16 @ Bt[N,K]bf16^T + bias (+Res))
// 128x128 tile, 256 threads = 4 waves (2x2 of 64x64), BK=32
// EPI: 0 none, 1 exact gelu, 2 residual add
// ---------------------------------------------------------------------------
template <int EPI, typename OutT>
__global__ __launch_bounds__(256) void mgemm(
    const u16* __restrict__ A, const u16* __restrict__ Bt,
    const float* __restrict__ bias, const float* __restrict__ Res,
    OutT* __restrict__ C, int M, int N, int Kd)
{
    __shared__ __align__(16) u16 As[128 * 40];
    __shared__ __align__(16) u16 Bs[128 * 40];
    int tid = threadIdx.x;
    int bm = blockIdx.y * 128, bn = blockIdx.x * 128;
    int wave = tid >> 6, lane = tid & 63;
    int wm = (wave >> 1) * 64, wn = (wave & 1) * 64;
    int lr = lane & 15, kg = lane >> 4;

    int s0 = tid, s1 = tid + 256;
    int r0 = s0 >> 2, g0 = (s0 & 3) * 8;
    int r1 = s1 >> 2, g1 = (s1 & 3) * 8;

    f32x4 acc[4][4] = {};

    for (int k0 = 0; k0 < Kd; k0 += 32) {
        uint4 a0 = *(const uint4*)(A + (size_t)(bm + r0) * Kd + k0 + g0);
        uint4 a1 = *(const uint4*)(A + (size_t)(bm + r1) * Kd + k0 + g1);
        uint4 b0 = *(const uint4*)(Bt + (size_t)(bn + r0) * Kd + k0 + g0);
        uint4 b1 = *(const uint4*)(Bt + (size_t)(bn + r1) * Kd + k0 + g1);
        __syncthreads();
        *(uint4*)&As[r0 * 40 + g0] = a0;
        *(uint4*)&As[r1 * 40 + g1] = a1;
        *(uint4*)&Bs[r0 * 40 + g0] = b0;
        *(uint4*)&Bs[r1 * 40 + g1] = b1;
        __syncthreads();
        bf16x8 af[4], bg[4];
        #pragma unroll
        for (int i = 0; i < 4; i++)
            af[i] = *(const bf16x8*)&As[(wm + i * 16 + lr) * 40 + kg * 8];
        #pragma unroll
        for (int j = 0; j < 4; j++)
            bg[j] = *(const bf16x8*)&Bs[(wn + j * 16 + lr) * 40 + kg * 8];
        #pragma unroll
        for (int i = 0; i < 4; i++)
            #pragma unroll
            for (int j = 0; j < 4; j++)
                acc[i][j] = __builtin_amdgcn_mfma_f32_16x16x32_bf16(
                    af[i], bg[j], acc[i][j], 0, 0, 0);
    }

    int crow = (lane >> 4) * 4;
    int ccol = lane & 15;
    #pragma unroll
    for (int i = 0; i < 4; i++) {
        #pragma unroll
        for (int j = 0; j < 4; j++) {
            int col = bn + wn + j * 16 + ccol;
            float bc = bias[col];
            #pragma unroll
            for (int r = 0; r < 4; r++) {
                int row = bm + wm + i * 16 + crow + r;
                float v = acc[i][j][r] + bc;
                if (EPI == 1) v = 0.5f * v * (1.0f + erff(v * 0.70710678118654752f));
                if (EPI == 2) v += Res[(size_t)row * N + col];
                if constexpr (sizeof(OutT) == 2)
                    C[(size_t)row * N + col] = f2b(v);
                else
                    C[(size_t)row * N + col] = v;
            }
        }
    }
}

// ---------------------------------------------------------------------------
// Chunked linear attention (qkv fp32: (B,L,768) q|k|v head-major D=64)
// Pass A (MFMA): per-chunk S[d][e] = sum_t k[t][d] v[t][e], z[d] = sum_t k[t][d]
// ---------------------------------------------------------------------------
__global__ __launch_bounds__(256) void chunk_sum_kernel(
    const float* __restrict__ QKV, float* __restrict__ S, float* __restrict__ Z)
{
    int blk = blockIdx.x;                  // (b*H+h)*NC + c
    int c = blk % NC_;
    int bh = blk / NC_;
    int h = bh % H_;
    int b = bh / H_;
    __shared__ __align__(16) u16 Kt[64 * 72];   // [d][t]
    __shared__ __align__(16) u16 Vt[64 * 72];   // [e][t]
    int tid = threadIdx.x;
    const size_t base = ((size_t)b * L_ + (size_t)c * CHK) * 768 + h * 64;
    for (int i = tid; i < 1024; i += 256) {
        int t = i >> 4, d4 = (i & 15) << 2;
        float4 k = *(const float4*)(QKV + base + (size_t)t * 768 + 256 + d4);
        float4 v = *(const float4*)(QKV + base + (size_t)t * 768 + 512 + d4);
        Kt[(d4 + 0) * 72 + t] = f2b(fmaxf(k.x, 0.f) + EPS_F);
        Kt[(d4 + 1) * 72 + t] = f2b(fmaxf(k.y, 0.f) + EPS_F);
        Kt[(d4 + 2) * 72 + t] = f2b(fmaxf(k.z, 0.f) + EPS_F);
        Kt[(d4 + 3) * 72 + t] = f2b(fmaxf(k.w, 0.f) + EPS_F);
        Vt[(d4 + 0) * 72 + t] = f2b(v.x);
        Vt[(d4 + 1) * 72 + t] = f2b(v.y);
        Vt[(d4 + 2) * 72 + t] = f2b(v.z);
        Vt[(d4 + 3) * 72 + t] = f2b(v.w);
    }
    __syncthreads();
    int wave = tid >> 6, lane = tid & 63;
    int lr = lane & 15, kg = lane >> 4;
    int wm = wave * 16;
    bf16x8 a0 = *(const bf16x8*)&Kt[(wm + lr) * 72 + kg * 8];
    bf16x8 a1 = *(const bf16x8*)&Kt[(wm + lr) * 72 + 32 + kg * 8];
    f32x4 acc[4] = {};
    #pragma unroll
    for (int j = 0; j < 4; j++) {
        bf16x8 b0 = *(const bf16x8*)&Vt[(j * 16 + lr) * 72 + kg * 8];
        bf16x8 b1 = *(const bf16x8*)&Vt[(j * 16 + lr) * 72 + 32 + kg * 8];
        acc[j] = __builtin_amdgcn_mfma_f32_16x16x32_bf16(a0, b0, acc[j], 0, 0, 0);
        acc[j] = __builtin_amdgcn_mfma_f32_16x16x32_bf16(a1, b1, acc[j], 0, 0, 0);
    }
    if (tid < 64) {
        float z = 0.f;
        #pragma unroll 8
        for (int t = 0; t < 64; t++) z += b2f(Kt[tid * 72 + t]);
        Z[(size_t)blk * 64 + tid] = z;
    }
    float* Sp = S + (size_t)blk * 4096;
    #pragma unroll
    for (int j = 0; j < 4; j++) {
        #pragma unroll
        for (int r = 0; r < 4; r++) {
            int d = wm + kg * 4 + r;
            int e = j * 16 + lr;
            Sp[d * 64 + e] = acc[j][r];
        }
    }
}

// Pass B: exclusive prefix over chunks (in place); one block per (b,h)
__global__ __launch_bounds__(256) void chunk_prefix_kernel(
    float* __restrict__ S, float* __restrict__ Z)
{
    int bh = blockIdx.x;
    int d = threadIdx.x >> 2;
    int e0 = (threadIdx.x & 3) << 4;
    float run[16] = {};
    float runz = 0.f;
    for (int c = 0; c < NC_; c++) {
        float* Sp = S + ((size_t)(bh * NC_ + c)) * 4096 + d * 64 + e0;
        #pragma unroll
        for (int j = 0; j < 16; j++) {
            float t = Sp[j];
            Sp[j] = run[j];
            run[j] += t;
        }
        if (e0 == 0) {
            float* Zp = Z + (size_t)(bh * NC_ + c) * 64 + d;
            float t = *Zp;
            *Zp = runz;
            runz += t;
        }
    }
}

// ---------------------------------------------------------------------------
// Pass C (MFMA): o = (Q@KVstate + tril(Q@K^T)@V) / max(Q.kz + rowsum, 1e-6)
// 256 threads = 4 waves; wave w owns rows 16w..16w+15 of the 64x64 chunk
// ---------------------------------------------------------------------------
__global__ __launch_bounds__(256) void chunk_out_kernel(
    const float* __restrict__ QKV, const float* __restrict__ KV,
    const float* __restrict__ KZ, u16* __restrict__ O)
{
    int blk = blockIdx.x;
    int c = blk % NC_;
    int bh = blk / NC_;
    int h = bh % H_;
    int b = bh / H_;
    __shared__ __align__(16) u16 Qb[64 * 72];    // [t][d]
    __shared__ __align__(16) u16 Kb[64 * 72];    // [t][d]
    __shared__ __align__(16) u16 Vt[64 * 72];    // [e][t]
    __shared__ __align__(16) u16 KVt[64 * 72];   // [e][d]
    __shared__ __align__(16) u16 Ps[64 * 72];    // [t][s] masked scores
    __shared__ float kzs[64];
    __shared__ float rows[64];
    __shared__ float invs[64];
    int tid = threadIdx.x;
    const size_t base = ((size_t)b * L_ + (size_t)c * CHK) * 768 + h * 64;
    for (int i = tid; i < 1024; i += 256) {
        int t = i >> 4, d4 = (i & 15) << 2;
        float4 q = *(const float4*)(QKV + base + (size_t)t * 768 + d4);
        float4 k = *(const float4*)(QKV + base + (size_t)t * 768 + 256 + d4);
        float4 v = *(const float4*)(QKV + base + (size_t)t * 768 + 512 + d4);
        ushort4 qu, ku;
        qu.x = f2b(fmaxf(q.x, 0.f) + EPS_F); qu.y = f2b(fmaxf(q.y, 0.f) + EPS_F);
        qu.z = f2b(fmaxf(q.z, 0.f) + EPS_F); qu.w = f2b(fmaxf(q.w, 0.f) + EPS_F);
        ku.x = f2b(fmaxf(k.x, 0.f) + EPS_F); ku.y = f2b(fmaxf(k.y, 0.f) + EPS_F);
        ku.z = f2b(fmaxf(k.z, 0.f) + EPS_F); ku.w = f2b(fmaxf(k.w, 0.f) + EPS_F);
        *(ushort4*)&Qb[t * 72 + d4] = qu;
        *(ushort4*)&Kb[t * 72 + d4] = ku;
        Vt[(d4 + 0) * 72 + t] = f2b(v.x);
        Vt[(d4 + 1) * 72 + t] = f2b(v.y);
        Vt[(d4 + 2) * 72 + t] = f2b(v.z);
        Vt[(d4 + 3) * 72 + t] = f2b(v.w);
        // KV state: [d][e] -> KVt[e][d]
        int d = t, e4 = d4;
        float4 s = *(const float4*)(KV + (size_t)blk * 4096 + d * 64 + e4);
        KVt[(e4 + 0) * 72 + d] = f2b(s.x);
        KVt[(e4 + 1) * 72 + d] = f2b(s.y);
        KVt[(e4 + 2) * 72 + d] = f2b(s.z);
        KVt[(e4 + 3) * 72 + d] = f2b(s.w);
    }
    if (tid < 64) kzs[tid] = KZ[(size_t)blk * 64 + tid];
    __syncthreads();

    int wave = tid >> 6, lane = tid & 63;
    int lr = lane & 15, kg = lane >> 4;
    int wm = wave * 16;

    bf16x8 aq0 = *(const bf16x8*)&Qb[(wm + lr) * 72 + kg * 8];
    bf16x8 aq1 = *(const bf16x8*)&Qb[(wm + lr) * 72 + 32 + kg * 8];

    // S_qk = Q @ K^T  (rows wm.., all 64 cols)
    f32x4 accs[4] = {};
    #pragma unroll
    for (int j = 0; j < 4; j++) {
        bf16x8 b0 = *(const bf16x8*)&Kb[(j * 16 + lr) * 72 + kg * 8];
        bf16x8 b1 = *(const bf16x8*)&Kb[(j * 16 + lr) * 72 + 32 + kg * 8];
        accs[j] = __builtin_amdgcn_mfma_f32_16x16x32_bf16(aq0, b0, accs[j], 0, 0, 0);
        accs[j] = __builtin_amdgcn_mfma_f32_16x16x32_bf16(aq1, b1, accs[j], 0, 0, 0);
    }
    // mask tril, accumulate row sums, write P to LDS
    float rsum[4] = {0.f, 0.f, 0.f, 0.f};
    #pragma unroll
    for (int j = 0; j < 4; j++) {
        #pragma unroll
        for (int r = 0; r < 4; r++) {
            int m = wm + kg * 4 + r;
            int n = j * 16 + lr;
            float v = (n <= m) ? accs[j][r] : 0.f;
            rsum[r] += v;
            Ps[m * 72 + n] = f2b(v);
        }
    }
    #pragma unroll
    for (int r = 0; r < 4; r++) {
        float s = rsum[r];
        s += __shfl_xor(s, 1, 64);
        s += __shfl_xor(s, 2, 64);
        s += __shfl_xor(s, 4, 64);
        s += __shfl_xor(s, 8, 64);
        if (lr == 0) rows[wm + kg * 4 + r] = s;
    }
    __syncthreads();

    // denominator (wave 0) runs concurrently with num MFMAs (all waves)
    if (tid < 64) {
        float den = rows[tid];
        float acc = 0.f;
        #pragma unroll 8
        for (int d = 0; d < 64; d++) acc += b2f(Qb[tid * 72 + d]) * kzs[d];
        invs[tid] = 1.f / fmaxf(den + acc, 1e-6f);
    }

    bf16x8 ap0 = *(const bf16x8*)&Ps[(wm + lr) * 72 + kg * 8];
    bf16x8 ap1 = *(const bf16x8*)&Ps[(wm + lr) * 72 + 32 + kg * 8];
    f32x4 accn[4] = {};
    #pragma unroll
    for (int j = 0; j < 4; j++) {
        bf16x8 b0 = *(const bf16x8*)&KVt[(j * 16 + lr) * 72 + kg * 8];
        bf16x8 b1 = *(const bf16x8*)&KVt[(j * 16 + lr) * 72 + 32 + kg * 8];
        accn[j] = __builtin_amdgcn_mfma_f32_16x16x32_bf16(aq0, b0, accn[j], 0, 0, 0);
        accn[j] = __builtin_amdgcn_mfma_f32_16x16x32_bf16(aq1, b1, accn[j], 0, 0, 0);
        bf16x8 c0 = *(const bf16x8*)&Vt[(j * 16 + lr) * 72 + kg * 8];
        bf16x8 c1 = *(const bf16x8*)&Vt[(j * 16 + lr) * 72 + 32 + kg * 8];
        accn[j] = __builtin_amdgcn_mfma_f32_16x16x32_bf16(ap0, c0, accn[j], 0, 0, 0);
        accn[j] = __builtin_amdgcn_mfma_f32_16x16x32_bf16(ap1, c1, accn[j], 0, 0, 0);
    }
    __syncthreads();

    u16* Op = O + ((size_t)b * L_ + (size_t)c * CHK) * E_ + h * 64;
    #pragma unroll
    for (int j = 0; j < 4; j++) {
        #pragma unroll
        for (int r = 0; r < 4; r++) {
            int m = wm + kg * 4 + r;
            int e = j * 16 + lr;
            Op[(size_t)m * E_ + e] = f2b(accn[j][r] * invs[m]);
        }
    }
}

// ---------------------------------------------------------------------------
// Prediction head: out[b,t,na] = y[b, 3t+1, :] . pred_w[:,na] + pred_b[na]
// ---------------------------------------------------------------------------
__global__ __launch_bounds__(256) void pred_kernel(
    const float* __restrict__ Y, const float* __restrict__ W,
    const float* __restrict__ bias, float* __restrict__ Out)
{
    int idx = blockIdx.x * 256 + threadIdx.x;
    if (idx >= B_ * K_ * NA_) return;
    int na = idx % NA_;
    int t = (idx / NA_) % K_;
    int b = idx / (NA_ * K_);
    const float* y = Y + ((size_t)b * L_ + 3 * t + 1) * E_;
    float acc = bias[na];
    #pragma unroll 8
    for (int e = 0; e < E_; e++) acc += y[e] * W[e * NA_ + na];
    Out[idx] = acc;
}

// ---------------------------------------------------------------------------
extern "C" void kernel_launch(void* const* d_in, const int* in_sizes, int n_in,
                              void* d_out, int out_size, void* d_ws, size_t ws_size,
                              hipStream_t stream) {
    const float* rtg      = (const float*)d_in[0];
    const float* state    = (const float*)d_in[1];
    const float* action   = (const float*)d_in[2];
    const float* rtg_w    = (const float*)d_in[3];
    const float* rtg_b    = (const float*)d_in[4];
    const float* state_w  = (const float*)d_in[5];
    const float* state_b  = (const float*)d_in[6];
    const float* action_w = (const float*)d_in[7];
    const float* action_b = (const float*)d_in[8];
    const float* pos_emb  = (const float*)d_in[9];
    const float* norm1_g  = (const float*)d_in[10];
    const float* norm1_b  = (const float*)d_in[11];
    const float* qkv_w    = (const float*)d_in[12];
    const float* qkv_b    = (const float*)d_in[13];
    const float* out_w    = (const float*)d_in[14];
    const float* out_b    = (const float*)d_in[15];
    const float* norm2_g  = (const float*)d_in[16];
    const float* norm2_b  = (const float*)d_in[17];
    const float* ffn1_w   = (const float*)d_in[18];
    const float* ffn1_b   = (const float*)d_in[19];
    const float* ffn2_w   = (const float*)d_in[20];
    const float* ffn2_b   = (const float*)d_in[21];
    const float* normf_g  = (const float*)d_in[22];
    const float* normf_b  = (const float*)d_in[23];
    const float* pred_w   = (const float*)d_in[24];
    const float* pred_b   = (const float*)d_in[25];
    float* out = (float*)d_out;

    // workspace layout
    float* ws = (float*)d_ws;
    float* x    = ws;                        // 786432 f
    float* qkv  = x + 786432;                // 2359296 f
    float* S    = qkv + 2359296;             // 786432 f
    float* Z    = S + 786432;                // 12288 f
    float* yf   = Z + 12288;                 // 786432 f
    u16*   yb   = (u16*)(yf + 786432);       // 786432 u16
    u16*   att  = yb + 786432;               // 786432
    u16*   h1   = att + 786432;              // 3145728
    u16*   qkvT = h1 + 3145728;              // 393216
    u16*   outT = qkvT + 393216;             // 131072
    u16*   f1T  = outT + 131072;             // 524288
    u16*   f2T  = f1T + 524288;              // 524288

    wconv_kernel<<<1536, 256, 0, stream>>>(qkv_w, out_w, ffn1_w, ffn2_w,
                                           qkvT, outT, f1T, f2T);
    embed_kernel<<<(B_ * L_ * E_) / 256, 256, 0, stream>>>(
        rtg, state, action, rtg_w, rtg_b, state_w, state_b,
        action_w, action_b, pos_emb, x);

    for (int i = 0; i < NL_; i++) {
        ln_kernel<u16><<<M_ / 4, 256, 0, stream>>>(
            x, norm1_g + i * E_, norm1_b + i * E_, yb);
        mgemm<0, float><<<dim3(768 / 128, M_ / 128), 256, 0, stream>>>(
            yb, qkvT + (size_t)i * 196608, qkv_b + i * 768, nullptr, qkv,
            M_, 768, E_);
        chunk_sum_kernel<<<B_ * H_ * NC_, 256, 0, stream>>>(qkv, S, Z);
        chunk_prefix_kernel<<<B_ * H_, 256, 0, stream>>>(S, Z);
        chunk_out_kernel<<<B_ * H_ * NC_, 256, 0, stream>>>(qkv, S, Z, att);
        mgemm<2, float><<<dim3(E_ / 128, M_ / 128), 256, 0, stream>>>(
            att, outT + (size_t)i * 65536, out_b + i * E_, x, x,
            M_, E_, E_);
        ln_kernel<u16><<<M_ / 4, 256, 0, stream>>>(
            x, norm2_g + i * E_, norm2_b + i * E_, yb);
        mgemm<1, u16><<<dim3(FF_ / 128, M_ / 128), 256, 0, stream>>>(
            yb, f1T + (size_t)i * 262144, ffn1_b + i * FF_, nullptr, h1,
            M_, FF_, E_);
        mgemm<2, float><<<dim3(E_ / 128, M_ / 128), 256, 0, stream>>>(
            h1, f2T + (size_t)i * 262144, ffn2_b + i * E_, x, x,
            M_, E_, FF_);
    }
    ln_kernel<float><<<M_ / 4, 256, 0, stream>>>(x, normf_g, normf_b, yf);
    pred_kernel<<<(B_ * K_ * NA_ + 255) / 256, 256, 0, stream>>>(
        yf, pred_w, pred_b, out);
}